// Round 8
// baseline (230.269 us; speedup 1.0000x reference)
//
#include <hip/hip_runtime.h>
#include <hip/hip_bf16.h>
#include <stdint.h>
#include <stddef.h>

// MatchLSTMAttention: B=64, T=2048, inp_p=inp_q=out=512
// out[b] = concat(input_p[b], z[b]); z = softmax_t(w . tanh(prq[b] + iq[b,t] @ Wq^T)) @ iq[b]
// R8: single-pass fused kernel, BARRIER-FREE main loop.
//  - A-panel (128 rows x 512 k) converted to bf16 in LDS once (XOR-chunk layout).
//  - B fragments loaded from L2-resident Wq_bf directly into registers (no LDS, no barriers).
//  - Block-local logits + softmax + z-partial (reusing the LDS A-panel).

typedef __attribute__((ext_vector_type(8))) short short8;
typedef __attribute__((ext_vector_type(4))) float f32x4;

__device__ __forceinline__ short8 cvt8(float4 a, float4 b) {
    union { __hip_bfloat162 h[4]; short8 s; } u;
    u.h[0] = __float22bfloat162_rn(make_float2(a.x, a.y));
    u.h[1] = __float22bfloat162_rn(make_float2(a.z, a.w));
    u.h[2] = __float22bfloat162_rn(make_float2(b.x, b.y));
    u.h[3] = __float22bfloat162_rn(make_float2(b.z, b.w));
    return u.s;
}

__device__ __forceinline__ float bf2f(unsigned short u) {
    unsigned v = (unsigned)u << 16;
    return __builtin_bit_cast(float, v);
}

// ---------- kernel 0: Wq fp32 -> bf16 ----------
__global__ __launch_bounds__(256) void k_convert8(const float* __restrict__ src,
                                                  unsigned short* __restrict__ dst) {
    size_t i = ((size_t)blockIdx.x * 256 + threadIdx.x) * 8;
    float4 a = *(const float4*)(src + i);
    float4 b = *(const float4*)(src + i + 4);
    *(short8*)(dst + i) = cvt8(a, b);
}

// ---------- kernel 1: prq[b,o] = ip.Wp^T + h.Wr^T + bp + bq + br ----------
__global__ __launch_bounds__(256) void k_prq(
        const float* __restrict__ ip, const float* __restrict__ h,
        const float* __restrict__ Wp, const float* __restrict__ Wr,
        const float* __restrict__ bp, const float* __restrict__ bq,
        const float* __restrict__ br, float* __restrict__ prq) {
    __shared__ float ip_lds[64][68];
    __shared__ float h_lds[64][68];
    __shared__ float wp_lds[8][68];
    __shared__ float wr_lds[8][68];
    const int tid = threadIdx.x;
    const int o0 = blockIdx.x * 8;
    const int bb = tid >> 3;
    const int oo = tid & 7;
    float acc0 = 0.f, acc1 = 0.f;
    const int lrow = tid >> 2;
    const int lcol = (tid & 3) * 16;
    for (int kc = 0; kc < 512; kc += 64) {
        #pragma unroll
        for (int j = 0; j < 16; j += 4) {
            float4 v = *(const float4*)(ip + lrow * 512 + kc + lcol + j);
            ip_lds[lrow][lcol + j] = v.x; ip_lds[lrow][lcol + j + 1] = v.y;
            ip_lds[lrow][lcol + j + 2] = v.z; ip_lds[lrow][lcol + j + 3] = v.w;
            float4 u = *(const float4*)(h + lrow * 512 + kc + lcol + j);
            h_lds[lrow][lcol + j] = u.x; h_lds[lrow][lcol + j + 1] = u.y;
            h_lds[lrow][lcol + j + 2] = u.z; h_lds[lrow][lcol + j + 3] = u.w;
        }
        if (tid < 128) {
            int r = tid >> 4, c = (tid & 15) * 4;
            float4 v = *(const float4*)(Wp + (size_t)(o0 + r) * 512 + kc + c);
            wp_lds[r][c] = v.x; wp_lds[r][c + 1] = v.y; wp_lds[r][c + 2] = v.z; wp_lds[r][c + 3] = v.w;
        } else {
            int t2 = tid - 128;
            int r = t2 >> 4, c = (t2 & 15) * 4;
            float4 v = *(const float4*)(Wr + (size_t)(o0 + r) * 512 + kc + c);
            wr_lds[r][c] = v.x; wr_lds[r][c + 1] = v.y; wr_lds[r][c + 2] = v.z; wr_lds[r][c + 3] = v.w;
        }
        __syncthreads();
        #pragma unroll 4
        for (int k = 0; k < 64; ++k) {
            float wpv = wp_lds[oo][k], wrv = wr_lds[oo][k];
            acc0 += ip_lds[bb][k] * wpv + h_lds[bb][k] * wrv;
            acc1 += ip_lds[bb + 32][k] * wpv + h_lds[bb + 32][k] * wrv;
        }
        __syncthreads();
    }
    const int o = o0 + oo;
    float base = bp[o] + bq[o] + br[o];
    prq[bb * 512 + o] = acc0 + base;
    prq[(bb + 32) * 512 + o] = acc1 + base;
}

// ---------- fused kernel ----------
// 1024 blocks x 512 thr. Block = 128 m-rows (16 blocks per b).
// A_p layout: ushort A_p[row*512 + ((c ^ (row&7))<<3)], c = k-chunk 0..63 (8 bf16 each).
__global__ __launch_bounds__(512, 1) void k_big(
        const float* __restrict__ iq, const unsigned short* __restrict__ Wq_bf,
        const float* __restrict__ prq, const float* __restrict__ wv,
        float* __restrict__ zp_g, float* __restrict__ ms_g) {
    __shared__ unsigned short A_p[128 * 512];   // 128 KB
    __shared__ float w_lds[512];
    __shared__ float prq_lds[512];
    __shared__ float red[4][128];
    __shared__ float e_lds[128];
    __shared__ float zsc[8][512];               // 16 KB

    const int tid = threadIdx.x;
    const int bid = blockIdx.x;
    const int m0 = bid * 128;
    const int b = bid >> 4;

    w_lds[tid] = wv[tid];
    prq_lds[tid] = prq[b * 512 + tid];

    // ---- stage A panel (fp32 -> bf16), 16 rounds, coalesced 128B row-segments ----
    {
        const int srow = tid >> 2;
        const float* gbase = iq + (size_t)(m0 + srow) * 512;
        #pragma unroll 4
        for (int r = 0; r < 16; ++r) {
            int c = (tid & 3) + r * 4;
            float4 v0 = *(const float4*)(gbase + c * 8);
            float4 v1 = *(const float4*)(gbase + c * 8 + 4);
            *(short8*)&A_p[srow * 512 + ((c ^ (srow & 7)) << 3)] = cvt8(v0, v1);
        }
    }
    __syncthreads();

    // ---- barrier-free GEMM main loop ----
    const int lane = tid & 63;
    const int wave = tid >> 6;
    const int wm = wave >> 2;                   // 0..1 (64-row half)
    const int wn = wave & 3;                    // 0..3 (128-col quarter)
    const int r16 = lane & 15;
    const int cc = lane >> 4;                   // k sub-chunk 0..3
    const int xr = r16 & 7;

    f32x4 acc[4][8];
    #pragma unroll
    for (int i = 0; i < 4; ++i)
        #pragma unroll
        for (int j = 0; j < 8; ++j) acc[i][j] = (f32x4){0.f, 0.f, 0.f, 0.f};

    const unsigned short* bbase = Wq_bf + ((size_t)(wn * 128 + r16)) * 512 + cc * 8;
    const int arow0 = (wm * 64 + r16) * 512;

    #pragma unroll 2
    for (int kc = 0; kc < 16; ++kc) {
        short8 bf[8];
        #pragma unroll
        for (int nf = 0; nf < 8; ++nf)
            bf[nf] = *(const short8*)(bbase + (size_t)nf * 16 * 512 + kc * 32);
        short8 af[4];
        #pragma unroll
        for (int mf = 0; mf < 4; ++mf) {
            int c = kc * 4 + cc;
            af[mf] = *(const short8*)&A_p[arow0 + mf * 16 * 512 + (((c ^ xr)) << 3)];
        }
        #pragma unroll
        for (int nf = 0; nf < 8; ++nf) {
            #pragma unroll
            for (int mf = 0; mf < 4; ++mf)
                acc[mf][nf] = __builtin_amdgcn_mfma_f32_16x16x32_bf16(af[mf], bf[nf], acc[mf][nf], 0, 0, 0);
        }
    }

    // ---- logits: part[mf][j] = sum over this wave's 128 cols of w[c]*tanh(acc+prq[c]) ----
    float part[4][4];
    #pragma unroll
    for (int mf = 0; mf < 4; ++mf)
        #pragma unroll
        for (int j = 0; j < 4; ++j) part[mf][j] = 0.f;

    #pragma unroll
    for (int nf = 0; nf < 8; ++nf) {
        int c = wn * 128 + nf * 16 + r16;
        float wc = w_lds[c];
        float pc = prq_lds[c];
        #pragma unroll
        for (int mf = 0; mf < 4; ++mf) {
            #pragma unroll
            for (int j = 0; j < 4; ++j) {
                float x = acc[mf][nf][j] + pc;
                float e = __expf(2.f * x);               // fast tanh
                part[mf][j] += wc * (1.f - 2.f / (e + 1.f));
            }
        }
    }
    #pragma unroll
    for (int mf = 0; mf < 4; ++mf)
        #pragma unroll
        for (int j = 0; j < 4; ++j) {
            float v = part[mf][j];
            v += __shfl_xor(v, 1);
            v += __shfl_xor(v, 2);
            v += __shfl_xor(v, 4);
            v += __shfl_xor(v, 8);
            part[mf][j] = v;
        }
    if (r16 == 0) {
        #pragma unroll
        for (int mf = 0; mf < 4; ++mf)
            #pragma unroll
            for (int j = 0; j < 4; ++j)
                red[wn][wm * 64 + mf * 16 + cc * 4 + j] = part[mf][j];
    }
    __syncthreads();

    // ---- block-local softmax over 128 rows ----
    if (tid < 128)
        e_lds[tid] = red[0][tid] + red[1][tid] + red[2][tid] + red[3][tid];
    __syncthreads();
    if (tid < 64) {
        float l0 = e_lds[tid], l1 = e_lds[tid + 64];
        float m = fmaxf(l0, l1);
        #pragma unroll
        for (int d = 1; d < 64; d <<= 1) m = fmaxf(m, __shfl_xor(m, d));
        float e0 = __expf(l0 - m), e1 = __expf(l1 - m);
        float s = e0 + e1;
        #pragma unroll
        for (int d = 1; d < 64; d <<= 1) s += __shfl_xor(s, d);
        e_lds[tid] = e0;
        e_lds[tid + 64] = e1;
        if (tid == 0) { ms_g[bid * 2] = m; ms_g[bid * 2 + 1] = s; }
    }
    __syncthreads();

    // ---- z partial: zp[q] = sum_t e_t * A_p[t][q] (LDS re-read) ----
    {
        const int c = tid & 63;                 // q-chunk (8 q's)
        const int ts = tid >> 6;                // t-slice (16 t's)
        float zq[8];
        #pragma unroll
        for (int k = 0; k < 8; ++k) zq[k] = 0.f;
        #pragma unroll 4
        for (int ti = 0; ti < 16; ++ti) {
            int t = ts * 16 + ti;
            float ev = e_lds[t];
            short8 av = *(const short8*)&A_p[t * 512 + ((c ^ (t & 7)) << 3)];
            #pragma unroll
            for (int k = 0; k < 8; ++k) zq[k] += ev * bf2f((unsigned short)av[k]);
        }
        *(float4*)&zsc[ts][c * 8]     = make_float4(zq[0], zq[1], zq[2], zq[3]);
        *(float4*)&zsc[ts][c * 8 + 4] = make_float4(zq[4], zq[5], zq[6], zq[7]);
    }
    __syncthreads();
    {
        float z = 0.f;
        #pragma unroll
        for (int w = 0; w < 8; ++w) z += zsc[w][tid];
        zp_g[(size_t)bid * 512 + tid] = z;
    }
}

// ---------- combine: merge 16 per-chunk partials per b; write out ----------
__global__ __launch_bounds__(512) void k_comb(const float* __restrict__ zp,
                                              const float* __restrict__ ms,
                                              const float* __restrict__ ip,
                                              float* __restrict__ out) {
    const int b = blockIdx.x, tid = threadIdx.x;
    __shared__ float mm[16], ssv[16];
    if (tid < 16) {
        mm[tid] = ms[(b * 16 + tid) * 2];
        ssv[tid] = ms[(b * 16 + tid) * 2 + 1];
    }
    __syncthreads();
    float M = -1e30f;
    #pragma unroll
    for (int i = 0; i < 16; ++i) M = fmaxf(M, mm[i]);
    float S = 0.f, z = 0.f;
    #pragma unroll 4
    for (int i = 0; i < 16; ++i) {
        float sc = __expf(mm[i] - M);
        S += ssv[i] * sc;
        z += sc * zp[(size_t)(b * 16 + i) * 512 + tid];
    }
    out[b * 1024 + 512 + tid] = z / S;
    out[b * 1024 + tid] = ip[b * 512 + tid];
}

extern "C" void kernel_launch(void* const* d_in, const int* in_sizes, int n_in,
                              void* d_out, int out_size, void* d_ws, size_t ws_size,
                              hipStream_t stream) {
    const float* input_p = (const float*)d_in[0];
    const float* input_q = (const float*)d_in[1];
    const float* h_tm1   = (const float*)d_in[2];
    const float* Wp      = (const float*)d_in[3];
    const float* bp      = (const float*)d_in[4];
    const float* Wq      = (const float*)d_in[5];
    const float* bq      = (const float*)d_in[6];
    const float* Wr      = (const float*)d_in[7];
    const float* br      = (const float*)d_in[8];
    const float* wv      = (const float*)d_in[9];
    float* out = (float*)d_out;

    char* ws = (char*)d_ws;
    unsigned short* Wq_bf = (unsigned short*)ws;            // 512 KB
    float* prq  = (float*)(ws + 512 * 1024);                // 128 KB
    float* ms   = (float*)(ws + 640 * 1024);                // 8 KB (1024 x 2)
    float* zp   = (float*)(ws + 1024 * 1024);               // 2 MB (1024 x 512)

    k_convert8<<<dim3(128), dim3(256), 0, stream>>>(Wq, Wq_bf);
    k_prq<<<dim3(64), dim3(256), 0, stream>>>(input_p, h_tm1, Wp, Wr, bp, bq, br, prq);
    k_big<<<dim3(1024), dim3(512), 0, stream>>>(input_q, Wq_bf, prq, wv, zp, ms);
    k_comb<<<dim3(64), dim3(512), 0, stream>>>(zp, ms, input_p, out);
}

// Round 9
// 218.627 us; speedup vs baseline: 1.0533x; 1.0533x over previous
//
#include <hip/hip_runtime.h>
#include <hip/hip_bf16.h>
#include <stdint.h>
#include <stddef.h>

// MatchLSTMAttention: B=64, T=2048, inp_p=inp_q=out=512
// out[b] = concat(input_p[b], z[b]); z = softmax_t(w . tanh(prq[b] + iq[b,t] @ Wq^T)) @ iq[b]
// R9: fused single-pass. Block = 64 t-rows x full N=512, 1024 thr (16 waves, 2m x 8n).
//  - A panel staged ONCE (16 slices [64][32] bf16, R5-proven XOR layout, reused for z).
//  - k-loop stages only B (32 KB/step) via global_load_lds dbuf + counted vmcnt (R6-proven).
//  - Block-local logits -> softmax -> z partial; tiny combine kernel.

typedef __attribute__((ext_vector_type(8))) short short8;
typedef __attribute__((ext_vector_type(4))) float f32x4;

__device__ __forceinline__ short8 cvt8(float4 a, float4 b) {
    union { __hip_bfloat162 h[4]; short8 s; } u;
    u.h[0] = __float22bfloat162_rn(make_float2(a.x, a.y));
    u.h[1] = __float22bfloat162_rn(make_float2(a.z, a.w));
    u.h[2] = __float22bfloat162_rn(make_float2(b.x, b.y));
    u.h[3] = __float22bfloat162_rn(make_float2(b.z, b.w));
    return u.s;
}

__device__ __forceinline__ float bf2f(unsigned short u) {
    unsigned v = (unsigned)u << 16;
    return __builtin_bit_cast(float, v);
}

__device__ __forceinline__ void gload_lds16(const void* g, void* l) {
    __builtin_amdgcn_global_load_lds(
        (const __attribute__((address_space(1))) unsigned int*)g,
        (__attribute__((address_space(3))) unsigned int*)l, 16, 0, 0);
}

// ---------- kernel 0: Wq fp32 -> bf16 ----------
__global__ __launch_bounds__(256) void k_convert8(const float* __restrict__ src,
                                                  unsigned short* __restrict__ dst) {
    size_t i = ((size_t)blockIdx.x * 256 + threadIdx.x) * 8;
    float4 a = *(const float4*)(src + i);
    float4 b = *(const float4*)(src + i + 4);
    *(short8*)(dst + i) = cvt8(a, b);
}

// ---------- kernel 1: prq[b,o] = ip.Wp^T + h.Wr^T + bp + bq + br ----------
__global__ __launch_bounds__(256) void k_prq(
        const float* __restrict__ ip, const float* __restrict__ h,
        const float* __restrict__ Wp, const float* __restrict__ Wr,
        const float* __restrict__ bp, const float* __restrict__ bq,
        const float* __restrict__ br, float* __restrict__ prq) {
    __shared__ float ip_lds[64][68];
    __shared__ float h_lds[64][68];
    __shared__ float wp_lds[8][68];
    __shared__ float wr_lds[8][68];
    const int tid = threadIdx.x;
    const int o0 = blockIdx.x * 8;
    const int bb = tid >> 3;
    const int oo = tid & 7;
    float acc0 = 0.f, acc1 = 0.f;
    const int lrow = tid >> 2;
    const int lcol = (tid & 3) * 16;
    for (int kc = 0; kc < 512; kc += 64) {
        #pragma unroll
        for (int j = 0; j < 16; j += 4) {
            float4 v = *(const float4*)(ip + lrow * 512 + kc + lcol + j);
            ip_lds[lrow][lcol + j] = v.x; ip_lds[lrow][lcol + j + 1] = v.y;
            ip_lds[lrow][lcol + j + 2] = v.z; ip_lds[lrow][lcol + j + 3] = v.w;
            float4 u = *(const float4*)(h + lrow * 512 + kc + lcol + j);
            h_lds[lrow][lcol + j] = u.x; h_lds[lrow][lcol + j + 1] = u.y;
            h_lds[lrow][lcol + j + 2] = u.z; h_lds[lrow][lcol + j + 3] = u.w;
        }
        if (tid < 128) {
            int r = tid >> 4, c = (tid & 15) * 4;
            float4 v = *(const float4*)(Wp + (size_t)(o0 + r) * 512 + kc + c);
            wp_lds[r][c] = v.x; wp_lds[r][c + 1] = v.y; wp_lds[r][c + 2] = v.z; wp_lds[r][c + 3] = v.w;
        } else {
            int t2 = tid - 128;
            int r = t2 >> 4, c = (t2 & 15) * 4;
            float4 v = *(const float4*)(Wr + (size_t)(o0 + r) * 512 + kc + c);
            wr_lds[r][c] = v.x; wr_lds[r][c + 1] = v.y; wr_lds[r][c + 2] = v.z; wr_lds[r][c + 3] = v.w;
        }
        __syncthreads();
        #pragma unroll 4
        for (int k = 0; k < 64; ++k) {
            float wpv = wp_lds[oo][k], wrv = wr_lds[oo][k];
            acc0 += ip_lds[bb][k] * wpv + h_lds[bb][k] * wrv;
            acc1 += ip_lds[bb + 32][k] * wpv + h_lds[bb + 32][k] * wrv;
        }
        __syncthreads();
    }
    const int o = o0 + oo;
    float base = bp[o] + bq[o] + br[o];
    prq[bb * 512 + o] = acc0 + base;
    prq[(bb + 32) * 512 + o] = acc1 + base;
}

// ---------- fused kernel ----------
// 2048 blocks x 1024 thr. Block = 64 t-rows (32 blocks per b). 16 waves = 2m(32) x 8n(64).
union BZ { unsigned short B[2][16384]; float zsc[8][512]; };   // 64 KB / 16 KB

__global__ __launch_bounds__(1024, 4) void k_fused(
        const float* __restrict__ iq, const unsigned short* __restrict__ Wq_bf,
        const float* __restrict__ prq, const float* __restrict__ wv,
        float* __restrict__ zp_g, float* __restrict__ ms_g) {
    __shared__ unsigned short A_p[16][2064];   // 66 KB: 16 k-slices of [64 rows][32 k]
    __shared__ BZ sh;                          // 64 KB B dbuf / 16 KB z scratch
    __shared__ float w_lds[512];
    __shared__ float prq_lds[512];
    __shared__ float red[8][64];
    __shared__ float e_lds[64];

    const int tid = threadIdx.x;
    const int bid = blockIdx.x;
    const int m0 = bid * 64;
    const int b = bid >> 5;

    if (tid < 512) {
        w_lds[tid] = wv[tid];
        prq_lds[tid] = prq[b * 512 + tid];
    }

    // ---- stage A panel once: 64 rows x 512 k fp32 -> bf16, 4 chunks/thread ----
    {
        const int row = tid >> 4;
        const float* g = iq + (size_t)(m0 + row) * 512;
        #pragma unroll
        for (int i = 0; i < 4; ++i) {
            int gc = (tid & 15) + i * 16;          // 8-float chunk 0..63
            float4 v0 = *(const float4*)(g + gc * 8);
            float4 v1 = *(const float4*)(g + gc * 8 + 4);
            *(short8*)&A_p[gc >> 2][row * 32 + (((gc & 3) ^ ((row >> 1) & 3)) << 3)] = cvt8(v0, v1);
        }
    }

    // ---- B staging sources (pre-swizzled; R6-verbatim scheme) ----
    const unsigned short *bsrc0, *bsrc1;
    {
        int r0 = tid >> 2, s0 = (tid & 3) ^ ((r0 >> 1) & 3);
        bsrc0 = Wq_bf + (size_t)r0 * 512 + (s0 << 3);
        int t1 = 1024 + tid, r1 = t1 >> 2, s1 = (t1 & 3) ^ ((r1 >> 1) & 3);
        bsrc1 = Wq_bf + (size_t)r1 * 512 + (s1 << 3);
    }
    const int wave = tid >> 6;

#define BSTAGE(S, BUF)                                                               \
    gload_lds16(bsrc0 + (S) * 32, (char*)&sh.B[BUF][0] + wave * 1024);               \
    gload_lds16(bsrc1 + (S) * 32, (char*)&sh.B[BUF][0] + 16384 + wave * 1024);

    BSTAGE(0, 0);
    asm volatile("s_waitcnt vmcnt(0) lgkmcnt(0)" ::: "memory");
    __builtin_amdgcn_sched_barrier(0);
    __builtin_amdgcn_s_barrier();

    // ---- k-loop: 16 steps, B dbuf, counted vmcnt, 2 barriers/step ----
    const int lane = tid & 63;
    const int wm = wave >> 3;                  // 0..1  (32-row half)
    const int ng = wave & 7;                   // 0..7  (64-col group)
    const int r16 = lane & 15;
    const int cc = lane >> 4;

    const int ar0 = wm * 32 + r16;
    const int ar1 = ar0 + 16;
    const int aoff0 = ar0 * 32 + ((cc ^ ((ar0 >> 1) & 3)) << 3);
    const int aoff1 = ar1 * 32 + ((cc ^ ((ar1 >> 1) & 3)) << 3);
    int boff[4];
    #pragma unroll
    for (int nf = 0; nf < 4; ++nf) {
        int brow = ng * 64 + nf * 16 + r16;
        boff[nf] = brow * 32 + ((cc ^ ((brow >> 1) & 3)) << 3);
    }

    f32x4 acc[2][4];
    #pragma unroll
    for (int i = 0; i < 2; ++i)
        #pragma unroll
        for (int j = 0; j < 4; ++j) acc[i][j] = (f32x4){0.f, 0.f, 0.f, 0.f};

    #pragma unroll 2
    for (int s = 0; s < 16; ++s) {
        if (s < 15) {
            BSTAGE(s + 1, (s + 1) & 1);
            asm volatile("s_waitcnt vmcnt(2)" ::: "memory");   // B(s) landed; B(s+1) in flight
        } else {
            asm volatile("s_waitcnt vmcnt(0)" ::: "memory");
        }
        __builtin_amdgcn_s_barrier();
        const unsigned short* Bb = &sh.B[s & 1][0];
        short8 af0 = *(const short8*)&A_p[s][aoff0];
        short8 af1 = *(const short8*)&A_p[s][aoff1];
        #pragma unroll
        for (int nf = 0; nf < 4; ++nf) {
            short8 bfr = *(const short8*)&Bb[boff[nf]];
            acc[0][nf] = __builtin_amdgcn_mfma_f32_16x16x32_bf16(af0, bfr, acc[0][nf], 0, 0, 0);
            acc[1][nf] = __builtin_amdgcn_mfma_f32_16x16x32_bf16(af1, bfr, acc[1][nf], 0, 0, 0);
        }
        asm volatile("s_waitcnt lgkmcnt(0)" ::: "memory");
        __builtin_amdgcn_s_barrier();
    }
#undef BSTAGE

    // ---- logits: part[mf][j] = sum over wave's 64 cols of w[c]*tanh(acc+prq[c]) ----
    float part[2][4];
    #pragma unroll
    for (int mf = 0; mf < 2; ++mf)
        #pragma unroll
        for (int j = 0; j < 4; ++j) part[mf][j] = 0.f;

    #pragma unroll
    for (int nf = 0; nf < 4; ++nf) {
        int c = ng * 64 + nf * 16 + r16;
        float wc = w_lds[c];
        float pc = prq_lds[c];
        #pragma unroll
        for (int mf = 0; mf < 2; ++mf) {
            #pragma unroll
            for (int j = 0; j < 4; ++j) {
                float x = acc[mf][nf][j] + pc;
                float e = __expf(2.f * x);               // fast tanh: 1 - 2/(e^2x+1)
                part[mf][j] += wc * (1.f - 2.f / (e + 1.f));
            }
        }
    }
    #pragma unroll
    for (int mf = 0; mf < 2; ++mf)
        #pragma unroll
        for (int j = 0; j < 4; ++j) {
            float v = part[mf][j];
            v += __shfl_xor(v, 1);
            v += __shfl_xor(v, 2);
            v += __shfl_xor(v, 4);
            v += __shfl_xor(v, 8);
            part[mf][j] = v;
        }
    if (r16 == 0) {
        #pragma unroll
        for (int mf = 0; mf < 2; ++mf)
            #pragma unroll
            for (int j = 0; j < 4; ++j)
                red[ng][wm * 32 + mf * 16 + cc * 4 + j] = part[mf][j];
    }
    __syncthreads();

    // ---- block-local softmax over 64 rows (wave 0) ----
    if (tid < 64) {
        float l = red[0][tid] + red[1][tid] + red[2][tid] + red[3][tid]
                + red[4][tid] + red[5][tid] + red[6][tid] + red[7][tid];
        float m = l;
        #pragma unroll
        for (int d = 1; d < 64; d <<= 1) m = fmaxf(m, __shfl_xor(m, d));
        float ev = __expf(l - m);
        float sv = ev;
        #pragma unroll
        for (int d = 1; d < 64; d <<= 1) sv += __shfl_xor(sv, d);
        e_lds[tid] = ev;
        if (tid == 0) { ms_g[bid * 2] = m; ms_g[bid * 2 + 1] = sv; }
    }
    __syncthreads();

    // ---- z partial: zp[q] = sum_t e_t * A[t][q]; A re-read from LDS ----
    {
        const int qg = tid & 127;              // 4 q's
        const int tg = tid >> 7;               // 8 t's
        const int q0 = qg * 4;
        const int sl = q0 >> 5;                // k-slice
        const int qc = (q0 >> 3) & 3;          // chunk within slice
        const int qo = q0 & 7;                 // 0 or 4
        float z0 = 0.f, z1 = 0.f, z2 = 0.f, z3 = 0.f;
        #pragma unroll
        for (int ti = 0; ti < 8; ++ti) {
            int t = tg * 8 + ti;
            float ev = e_lds[t];
            const unsigned short* ap = &A_p[sl][t * 32 + ((qc ^ ((t >> 1) & 3)) << 3) + qo];
            z0 += ev * bf2f(ap[0]);
            z1 += ev * bf2f(ap[1]);
            z2 += ev * bf2f(ap[2]);
            z3 += ev * bf2f(ap[3]);
        }
        *(float4*)&sh.zsc[tg][q0] = make_float4(z0, z1, z2, z3);
    }
    __syncthreads();
    if (tid < 512) {
        float z = 0.f;
        #pragma unroll
        for (int w = 0; w < 8; ++w) z += sh.zsc[w][tid];
        zp_g[(size_t)bid * 512 + tid] = z;
    }
}

// ---------- combine: merge 32 per-chunk partials per b; write out ----------
__global__ __launch_bounds__(512) void k_comb(const float* __restrict__ zp,
                                              const float* __restrict__ ms,
                                              const float* __restrict__ ip,
                                              float* __restrict__ out) {
    const int b = blockIdx.x, tid = threadIdx.x;
    __shared__ float mm[32], ssv[32];
    if (tid < 32) {
        mm[tid] = ms[(b * 32 + tid) * 2];
        ssv[tid] = ms[(b * 32 + tid) * 2 + 1];
    }
    __syncthreads();
    float M = -1e30f;
    #pragma unroll
    for (int i = 0; i < 32; ++i) M = fmaxf(M, mm[i]);
    float S = 0.f, z = 0.f;
    #pragma unroll 4
    for (int i = 0; i < 32; ++i) {
        float sc = __expf(mm[i] - M);
        S += ssv[i] * sc;
        z += sc * zp[(size_t)(b * 32 + i) * 512 + tid];
    }
    out[b * 1024 + 512 + tid] = z / S;
    out[b * 1024 + tid] = ip[b * 512 + tid];
}

extern "C" void kernel_launch(void* const* d_in, const int* in_sizes, int n_in,
                              void* d_out, int out_size, void* d_ws, size_t ws_size,
                              hipStream_t stream) {
    const float* input_p = (const float*)d_in[0];
    const float* input_q = (const float*)d_in[1];
    const float* h_tm1   = (const float*)d_in[2];
    const float* Wp      = (const float*)d_in[3];
    const float* bp      = (const float*)d_in[4];
    const float* Wq      = (const float*)d_in[5];
    const float* bq      = (const float*)d_in[6];
    const float* Wr      = (const float*)d_in[7];
    const float* br      = (const float*)d_in[8];
    const float* wv      = (const float*)d_in[9];
    float* out = (float*)d_out;

    char* ws = (char*)d_ws;
    unsigned short* Wq_bf = (unsigned short*)ws;            // 512 KB
    float* prq  = (float*)(ws + 512 * 1024);                // 128 KB
    float* ms   = (float*)(ws + 640 * 1024);                // 16 KB (2048 x 2)
    float* zp   = (float*)(ws + 1024 * 1024);               // 4 MB (2048 x 512)

    k_convert8<<<dim3(128), dim3(256), 0, stream>>>(Wq, Wq_bf);
    k_prq<<<dim3(64), dim3(256), 0, stream>>>(input_p, h_tm1, Wp, Wr, bp, bq, br, prq);
    k_fused<<<dim3(2048), dim3(1024), 0, stream>>>(input_q, Wq_bf, prq, wv, zp, ms);
    k_comb<<<dim3(64), dim3(512), 0, stream>>>(zp, ms, input_p, out);
}